// Round 11
// baseline (91.306 us; speedup 1.0000x reference)
//
#include <hip/hip_runtime.h>

#define NB 2
#define C 32
#define H 128
#define W 256
#define D 48
#define HW (H * W)

#define GRID 512        // 2 blocks/CU x 256 CU -> co-resident by construction
#define NBLK 512u

// phase 2: 12 d per block, 4 chunks
#define DCH 12
#define NCH (D / DCH)   // 4

// ---------------------------------------------------------------------------
// Persistent fused kernel, manual grid barrier.
// Phase 1 (tid<192): zkern v6 body. Block bid -> (xcd=bid&7, half, hi, n);
//   z[n][d][h][w] = sum_c x*y[w-d]; burst x-loads; 3 b128/c -> 32 FMA.
// Barrier: agent-scope counter in d_ws (+ release/acquire fences).
// Phase 2: fkern v7 body, 12-d chunks. Block -> (xcd, ch, p, pl, n);
//   thread (q, r, g2) owns 6 d x 4 w; 6 staged z-rows serve 2 output rows.
// LDS: union(ys 23.5KB, zs 74.3KB) = 74.3KB -> exactly 2 blocks/CU.
// ---------------------------------------------------------------------------
__global__ __launch_bounds__(256, 2) void fused_kern(const float* __restrict__ x,
                                                     const float* __restrict__ y,
                                                     const float* __restrict__ Ff,
                                                     const float* __restrict__ B,
                                                     float* __restrict__ out,
                                                     float* __restrict__ z,
                                                     unsigned int* __restrict__ cnt) {
    __shared__ __align__(16) union {
        float ys[C][184];          // phase 1
        float zs[DCH][6][264];     // phase 2 (74.25 KB)
    } sm;

    const int bid = blockIdx.x;
    const int tid = threadIdx.x;
    const int xcd = bid & 7;

    // ------------------------------ phase 1 ------------------------------
    if (tid < 192) {
        const int slot = bid >> 3;      // 0..63
        const int half = slot & 1;
        const int t2   = slot >> 1;     // 0..31
        const int hi   = t2 & 15;
        const int n    = t2 >> 4;
        const int h    = xcd * 16 + hi;

        const int q    = tid & 31;
        const int dg   = tid >> 5;      // 0..5
        const int d0   = dg * 8;

        const float* xrow = x + ((size_t)(n * C) * H + h) * (size_t)W;
        const float* yrow = y + ((size_t)(n * C) * H + h) * (size_t)W;
        const int ybase = 128 * half - 48;

#pragma unroll
        for (int it = 0; it < 8; ++it) {
            const int idx = it * 192 + tid;
            if (idx < 32 * 46) {
                const int r    = idx / 46;
                const int c4   = idx % 46;
                const int yidx = ybase + 4 * c4;
                float4 v = {0.f, 0.f, 0.f, 0.f};
                if (yidx >= 0 && yidx <= W - 4)
                    v = *(const float4*)(yrow + (size_t)r * HW + yidx);
                *(float4*)&sm.ys[r][4 * c4] = v;
            }
        }
        __syncthreads();

        float acc[8][4] = {};
        const int S0 = 4 * q + 40 - d0;
        const float* xcol = xrow + 128 * half + 4 * q;

#pragma unroll
        for (int cb = 0; cb < 2; ++cb) {
            float4 xr[16];
#pragma unroll
            for (int t = 0; t < 16; ++t)
                xr[t] = *(const float4*)(xcol + (size_t)(cb * 16 + t) * HW);

#pragma unroll
            for (int t = 0; t < 16; ++t) {
                const int c = cb * 16 + t;
                const float4 w0 = *(const float4*)&sm.ys[c][S0];
                const float4 w1 = *(const float4*)&sm.ys[c][S0 + 4];
                const float4 w2 = *(const float4*)&sm.ys[c][S0 + 8];
                const float win[12] = {w0.x, w0.y, w0.z, w0.w,
                                       w1.x, w1.y, w1.z, w1.w,
                                       w2.x, w2.y, w2.z, w2.w};
                const float xs[4] = {xr[t].x, xr[t].y, xr[t].z, xr[t].w};
#pragma unroll
                for (int k = 0; k < 8; ++k)
#pragma unroll
                    for (int o = 0; o < 4; ++o)
                        acc[k][o] += xs[o] * win[8 + o - k];
            }
        }

        float* zp = z + (((size_t)n * D + d0) * H + h) * (size_t)W + 128 * half + 4 * q;
#pragma unroll
        for (int k = 0; k < 8; ++k) {
            float4 v;
            v.x = acc[k][0]; v.y = acc[k][1]; v.z = acc[k][2]; v.w = acc[k][3];
            *(float4*)(zp + (size_t)k * HW) = v;
        }
    } else {
        __syncthreads();   // matches phase-1 staging barrier (all threads reach)
    }

    // --------------------------- grid barrier ----------------------------
    __syncthreads();       // drains this block's z stores (vmcnt0 before barrier)
    if (tid == 0) {
        __builtin_amdgcn_fence(__ATOMIC_RELEASE, "agent");   // L2 writeback
        __hip_atomic_fetch_add(cnt, 1u, __ATOMIC_RELAXED, __HIP_MEMORY_SCOPE_AGENT);
        unsigned int v = 0;
        long guard = 0;
        do {
            v = __hip_atomic_load(cnt, __ATOMIC_RELAXED, __HIP_MEMORY_SCOPE_AGENT);
        } while (v < NBLK && ++guard < 2000000);             // bounded: no hang
    }
    __syncthreads();
    __builtin_amdgcn_fence(__ATOMIC_ACQUIRE, "agent");       // L1/L2 invalidate

    // ------------------------------ phase 2 ------------------------------
    {
        const int slot = bid >> 3;       // 0..63
        const int ch   = slot & 3;       // d-chunk of 12
        const int t2   = slot >> 2;      // 0..15
        const int p    = t2 & 1;         // parity
        const int pl   = (t2 >> 1) & 3;  // pair index within band
        const int n    = t2 >> 3;        // batch
        const int h0   = xcd * 16 + 4 * pl + p;   // rows h0, h0+2
        const int d0   = ch * DCH;

        const int q    = tid & 63;        // w-quad: w = 4q+o
        const int r    = (tid >> 6) & 1;  // output row = h0 + 2r
        const int g2   = tid >> 7;        // d-half: d = d0 + 6*g2 + k
        const int hrow = h0 + 2 * r;

        // stage 72 rows (12 dd x 6 l) x 66 float4 ; l <-> hh = h0-4+2l
#pragma unroll
        for (int it = 0; it < 19; ++it) {
            const int idx = it * 256 + tid;
            if (idx < 72 * 66) {
                const int r2 = idx / 66;
                const int c4 = idx % 66;
                const int dd = r2 / 6;
                const int l  = r2 % 6;
                const int hh = h0 - 4 + 2 * l;
                float4 v = {0.f, 0.f, 0.f, 0.f};
                if (c4 >= 1 && c4 <= 64 && hh >= 0 && hh < H)
                    v = *(const float4*)(z + (((size_t)n * D + d0 + dd) * H + hh) * (size_t)W
                                           + 4 * c4 - 4);
                *(float4*)&sm.zs[dd][l][4 * c4] = v;
            }
        }

        const float4 bias = *(const float4*)(B + ((size_t)n * H + hrow) * (size_t)W + 4 * q);
        float acc[6][4];
#pragma unroll
        for (int k = 0; k < 6; ++k) {
            acc[k][0] = bias.x; acc[k][1] = bias.y;
            acc[k][2] = bias.z; acc[k][3] = bias.w;
        }

        __syncthreads();

#pragma unroll
        for (int i = 0; i < 5; ++i) {
            const int l = i + r;          // staged row serving tap-row i of row r
            float4 f[5];
#pragma unroll
            for (int jj = 0; jj < 5; ++jj)
                f[jj] = *(const float4*)(Ff + (((size_t)n * 25 + i * 5 + jj) * H + hrow)
                                               * (size_t)W + 4 * q);
            const float fs[5][4] = {
                {f[0].x, f[0].y, f[0].z, f[0].w},
                {f[1].x, f[1].y, f[1].z, f[1].w},
                {f[2].x, f[2].y, f[2].z, f[2].w},
                {f[3].x, f[3].y, f[3].z, f[3].w},
                {f[4].x, f[4].y, f[4].z, f[4].w}};

#pragma unroll
            for (int k = 0; k < 6; ++k) {
                const int dd = 6 * g2 + k;
                const float4 w0 = *(const float4*)&sm.zs[dd][l][4 * q];
                const float4 w1 = *(const float4*)&sm.zs[dd][l][4 * q + 4];
                const float4 w2 = *(const float4*)&sm.zs[dd][l][4 * q + 8];
                const float win[12] = {w0.x, w0.y, w0.z, w0.w,
                                       w1.x, w1.y, w1.z, w1.w,
                                       w2.x, w2.y, w2.z, w2.w};
#pragma unroll
                for (int jj = 0; jj < 5; ++jj)
#pragma unroll
                    for (int o = 0; o < 4; ++o)
                        acc[k][o] += fs[jj][o] * win[o + 2 * jj];
            }
        }

#pragma unroll
        for (int k = 0; k < 6; ++k) {
            float* op = out + (((size_t)n * D + d0 + 6 * g2 + k) * H + hrow) * (size_t)W + 4 * q;
            float4 v;
            v.x = acc[k][0]; v.y = acc[k][1]; v.z = acc[k][2]; v.w = acc[k][3];
            *(float4*)op = v;
        }
    }
}

// ---------------------------------------------------------------------------
// Fallback (workspace too small): fully fused naive version. Correctness only.
// ---------------------------------------------------------------------------
__global__ __launch_bounds__(256) void fused_naive(const float* __restrict__ x,
                                                   const float* __restrict__ y,
                                                   const float* __restrict__ Ff,
                                                   const float* __restrict__ B,
                                                   float* __restrict__ out) {
    const size_t idx = (size_t)blockIdx.x * 256 + threadIdx.x;
    if (idx >= (size_t)NB * D * H * W) return;
    const int w = (int)(idx % W);
    const int h = (int)((idx / W) % H);
    const int d = (int)((idx / ((size_t)W * H)) % D);
    const int n = (int)(idx / ((size_t)W * H * D));

    float acc = B[((size_t)n * H + h) * W + w];
#pragma unroll
    for (int i = 0; i < 5; ++i) {
        const int hh = h + 2 * i - 4;
        if (hh < 0 || hh >= H) continue;
#pragma unroll
        for (int j = 0; j < 5; ++j) {
            const int ww = w + 2 * j - 4;
            if (ww < 0 || ww >= W) continue;
            const int ws_ = ww - d;
            float zv = 0.f;
            if (ws_ >= 0) {
                const float* xp = x + (((size_t)n * C) * H + hh) * (size_t)W + ww;
                const float* yp = y + (((size_t)n * C) * H + hh) * (size_t)W + ws_;
                for (int c = 0; c < C; ++c)
                    zv += xp[(size_t)c * HW] * yp[(size_t)c * HW];
            }
            acc += Ff[(((size_t)n * 25 + i * 5 + j) * H + h) * (size_t)W + w] * zv;
        }
    }
    out[idx] = acc;
}

extern "C" void kernel_launch(void* const* d_in, const int* in_sizes, int n_in,
                              void* d_out, int out_size, void* d_ws, size_t ws_size,
                              hipStream_t stream) {
    const float* x = (const float*)d_in[0];
    const float* y = (const float*)d_in[1];
    const float* F = (const float*)d_in[2];
    const float* B = (const float*)d_in[3];
    float* out = (float*)d_out;

    const size_t zbytes = (size_t)NB * D * H * W * sizeof(float);

    if (ws_size >= zbytes + 64) {
        float* z = (float*)d_ws;
        unsigned int* cnt = (unsigned int*)((char*)d_ws + zbytes);
        hipMemsetAsync((void*)cnt, 0, sizeof(unsigned int), stream);
        fused_kern<<<GRID, 256, 0, stream>>>(x, y, F, B, out, z, cnt);
    } else {
        const size_t total = (size_t)NB * D * H * W;
        fused_naive<<<(int)((total + 255) / 256), 256, 0, stream>>>(x, y, F, B, out);
    }
}

// Round 12
// 29.359 us; speedup vs baseline: 3.1099x; 3.1099x over previous
//
#include <hip/hip_runtime.h>

#define NB 2
#define C 32
#define H 128
#define W 256
#define D 48
#define HW (H * W)

// ---------------------------------------------------------------------------
// zkern v8: z[n][d][h][w] = sum_c x[n][c][h][w]*y[n][c][h][w-d]  (0 if w<d)
// Grid NB*H*2*2 (=1024 blocks, 4/CU -> 3 waves/SIMD) x 192 threads.
// Block = (xcd band h/16, d-half dsel, w-half, hi, n); thread = (q, dg) owns
// 4 w x 4 d (d0 = 24*dsel + 4*dg). Window = 2 aligned ds_read_b128 per c
// (floats S..S+7, S = 4q+44-d0, S%4==0). Burst x-loads 8-deep.
// Same c-order as v6 -> bit-identical z.
// ---------------------------------------------------------------------------
__global__ __launch_bounds__(192, 3) void zkern(const float* __restrict__ x,
                                                const float* __restrict__ y,
                                                float* __restrict__ z) {
    const int s    = blockIdx.x;
    const int xcd  = s & 7;
    const int slot = s >> 3;        // 0..127
    const int dsel = slot & 1;      // d-half: 0 -> d 0..23, 1 -> d 24..47
    const int half = (slot >> 1) & 1;
    const int t2   = slot >> 2;     // 0..31
    const int hi   = t2 & 15;
    const int n    = t2 >> 4;
    const int h    = xcd * 16 + hi;

    const int tid  = threadIdx.x;
    const int q    = tid & 31;      // w-quad within half: w = 128*half + 4q + o
    const int dg   = tid >> 5;      // 0..5
    const int d0   = dsel * 24 + dg * 4;   // multiple of 4

    __shared__ __align__(16) float ys[C][184];   // col <-> y idx ybase+col

    const float* xrow = x + ((size_t)(n * C) * H + h) * (size_t)W;
    const float* yrow = y + ((size_t)(n * C) * H + h) * (size_t)W;
    const int ybase = 128 * half - 48;

    // stage: 32 rows x 46 float4 (zero where y idx OOB)
#pragma unroll
    for (int it = 0; it < 8; ++it) {
        const int idx = it * 192 + tid;
        if (idx < 32 * 46) {
            const int r    = idx / 46;
            const int c4   = idx % 46;
            const int yidx = ybase + 4 * c4;
            float4 v = {0.f, 0.f, 0.f, 0.f};
            if (yidx >= 0 && yidx <= W - 4)
                v = *(const float4*)(yrow + (size_t)r * HW + yidx);
            *(float4*)&ys[r][4 * c4] = v;
        }
    }
    __syncthreads();

    float acc[4][4] = {};
    const int S = 4 * q + 44 - d0;   // 0..168, 16B-aligned; floats S..S+7 used
    const float* xcol = xrow + 128 * half + 4 * q;

#pragma unroll
    for (int cb = 0; cb < 4; ++cb) {
        float4 xr[8];
#pragma unroll
        for (int t = 0; t < 8; ++t)
            xr[t] = *(const float4*)(xcol + (size_t)(cb * 8 + t) * HW);

#pragma unroll
        for (int t = 0; t < 8; ++t) {
            const int c = cb * 8 + t;
            const float4 w0 = *(const float4*)&ys[c][S];
            const float4 w1 = *(const float4*)&ys[c][S + 4];
            const float win[8] = {w0.x, w0.y, w0.z, w0.w,
                                  w1.x, w1.y, w1.z, w1.w};
            const float xs[4] = {xr[t].x, xr[t].y, xr[t].z, xr[t].w};
            // acc[k][o] += x[w] * y[w-(d0+k)] ; col = S + 4 + o - k
#pragma unroll
            for (int k = 0; k < 4; ++k)
#pragma unroll
                for (int o = 0; o < 4; ++o)
                    acc[k][o] += xs[o] * win[4 + o - k];
        }
    }

    float* zp = z + (((size_t)n * D + d0) * H + h) * (size_t)W + 128 * half + 4 * q;
#pragma unroll
    for (int k = 0; k < 4; ++k) {
        float4 v;
        v.x = acc[k][0]; v.y = acc[k][1]; v.z = acc[k][2]; v.w = acc[k][3];
        *(float4*)(zp + (size_t)k * HW) = v;
    }
}

// ---------------------------------------------------------------------------
// fkern v7 (byte-identical to round 9's passing version, grid 768):
// parity-pair blocks; block = (xcd band, d-chunk, parity, pair, n);
// thread = (q, r, g2) -> 4 d x 4 w; 6 staged z-rows serve both output rows
// (l = i + r); taps duplicated only x2. LDS 50.7 KB, all ops b128.
// ---------------------------------------------------------------------------
#define DCH 8
#define NCH (D / DCH)   // 6
#define FGRID 768       // 8 xcd * NCH * 16 (p, pl, n)

__global__ __launch_bounds__(256) void fkern(const float* __restrict__ z,
                                             const float* __restrict__ Ff,
                                             const float* __restrict__ B,
                                             float* __restrict__ out) {
    __shared__ __align__(16) float zs[DCH][6][264];   // col 0 <-> w=-4

    const int s    = blockIdx.x;
    const int xcd  = s & 7;          // h-band = rows [16*xcd, 16*xcd+15]
    const int slot = s >> 3;         // 0..95
    const int ch   = slot % NCH;     // d-chunk
    const int t2   = slot / NCH;     // 0..15
    const int p    = t2 & 1;         // parity
    const int pl   = (t2 >> 1) & 3;  // pair index within band
    const int n    = t2 >> 3;        // batch
    const int h0   = xcd * 16 + 4 * pl + p;   // rows h0, h0+2
    const int d0   = ch * DCH;

    const int tid  = threadIdx.x;
    const int q    = tid & 63;        // w-quad: w = 4q+o
    const int r    = (tid >> 6) & 1;  // output row = h0 + 2r
    const int g2   = tid >> 7;        // d-half: d = d0 + 4*g2 + k
    const int hrow = h0 + 2 * r;

    // stage 48 rows (8 dd x 6 l) x 66 float4 ; l <-> hh = h0-4+2l
#pragma unroll
    for (int it = 0; it < 13; ++it) {
        const int idx = it * 256 + tid;
        if (idx < 48 * 66) {
            const int r2 = idx / 66;
            const int c4 = idx % 66;
            const int dd = r2 / 6;
            const int l  = r2 % 6;
            const int hh = h0 - 4 + 2 * l;
            float4 v = {0.f, 0.f, 0.f, 0.f};
            if (c4 >= 1 && c4 <= 64 && hh >= 0 && hh < H)
                v = *(const float4*)(z + (((size_t)n * D + d0 + dd) * H + hh) * (size_t)W
                                       + 4 * c4 - 4);
            *(float4*)&zs[dd][l][4 * c4] = v;
        }
    }

    const float4 bias = *(const float4*)(B + ((size_t)n * H + hrow) * (size_t)W + 4 * q);
    float acc[4][4];
#pragma unroll
    for (int k = 0; k < 4; ++k) {
        acc[k][0] = bias.x; acc[k][1] = bias.y;
        acc[k][2] = bias.z; acc[k][3] = bias.w;
    }

    __syncthreads();

#pragma unroll
    for (int i = 0; i < 5; ++i) {
        const int l = i + r;          // staged row serving tap-row i of row r
        float4 f[5];
#pragma unroll
        for (int jj = 0; jj < 5; ++jj)
            f[jj] = *(const float4*)(Ff + (((size_t)n * 25 + i * 5 + jj) * H + hrow) * (size_t)W
                                        + 4 * q);
        const float fs[5][4] = {
            {f[0].x, f[0].y, f[0].z, f[0].w},
            {f[1].x, f[1].y, f[1].z, f[1].w},
            {f[2].x, f[2].y, f[2].z, f[2].w},
            {f[3].x, f[3].y, f[3].z, f[3].w},
            {f[4].x, f[4].y, f[4].z, f[4].w}};

#pragma unroll
        for (int k = 0; k < 4; ++k) {
            const int dd = 4 * g2 + k;
            const float4 w0 = *(const float4*)&zs[dd][l][4 * q];
            const float4 w1 = *(const float4*)&zs[dd][l][4 * q + 4];
            const float4 w2 = *(const float4*)&zs[dd][l][4 * q + 8];
            const float win[12] = {w0.x, w0.y, w0.z, w0.w,
                                   w1.x, w1.y, w1.z, w1.w,
                                   w2.x, w2.y, w2.z, w2.w};
            // out[hrow][w=4q+o] += f[i*5+jj] * z[d][h0-4+2l][w+2jj-4] ; col 4q+o+2jj
#pragma unroll
            for (int jj = 0; jj < 5; ++jj)
#pragma unroll
                for (int o = 0; o < 4; ++o)
                    acc[k][o] += fs[jj][o] * win[o + 2 * jj];
        }
    }

#pragma unroll
    for (int k = 0; k < 4; ++k) {
        float* op = out + (((size_t)n * D + d0 + 4 * g2 + k) * H + hrow) * (size_t)W + 4 * q;
        float4 v;
        v.x = acc[k][0]; v.y = acc[k][1]; v.z = acc[k][2]; v.w = acc[k][3];
        *(float4*)op = v;
    }
}

// ---------------------------------------------------------------------------
// Fallback (workspace too small): fully fused naive version. Correctness only.
// ---------------------------------------------------------------------------
__global__ __launch_bounds__(256) void fused_naive(const float* __restrict__ x,
                                                   const float* __restrict__ y,
                                                   const float* __restrict__ Ff,
                                                   const float* __restrict__ B,
                                                   float* __restrict__ out) {
    const size_t idx = (size_t)blockIdx.x * 256 + threadIdx.x;
    if (idx >= (size_t)NB * D * H * W) return;
    const int w = (int)(idx % W);
    const int h = (int)((idx / W) % H);
    const int d = (int)((idx / ((size_t)W * H)) % D);
    const int n = (int)(idx / ((size_t)W * H * D));

    float acc = B[((size_t)n * H + h) * W + w];
#pragma unroll
    for (int i = 0; i < 5; ++i) {
        const int hh = h + 2 * i - 4;
        if (hh < 0 || hh >= H) continue;
#pragma unroll
        for (int j = 0; j < 5; ++j) {
            const int ww = w + 2 * j - 4;
            if (ww < 0 || ww >= W) continue;
            const int ws_ = ww - d;
            float zv = 0.f;
            if (ws_ >= 0) {
                const float* xp = x + (((size_t)n * C) * H + hh) * (size_t)W + ww;
                const float* yp = y + (((size_t)n * C) * H + hh) * (size_t)W + ws_;
                for (int c = 0; c < C; ++c)
                    zv += xp[(size_t)c * HW] * yp[(size_t)c * HW];
            }
            acc += Ff[(((size_t)n * 25 + i * 5 + j) * H + h) * (size_t)W + w] * zv;
        }
    }
    out[idx] = acc;
}

extern "C" void kernel_launch(void* const* d_in, const int* in_sizes, int n_in,
                              void* d_out, int out_size, void* d_ws, size_t ws_size,
                              hipStream_t stream) {
    const float* x = (const float*)d_in[0];
    const float* y = (const float*)d_in[1];
    const float* F = (const float*)d_in[2];
    const float* B = (const float*)d_in[3];
    float* out = (float*)d_out;

    const size_t zbytes = (size_t)NB * D * H * W * sizeof(float);

    if (ws_size >= zbytes) {
        float* z = (float*)d_ws;
        zkern<<<NB * H * 2 * 2, 192, 0, stream>>>(x, y, z);
        fkern<<<FGRID, 256, 0, stream>>>(z, F, B, out);
    } else {
        const size_t total = (size_t)NB * D * H * W;
        fused_naive<<<(int)((total + 255) / 256), 256, 0, stream>>>(x, y, F, B, out);
    }
}

// Round 13
// 26.424 us; speedup vs baseline: 3.4554x; 1.1111x over previous
//
#include <hip/hip_runtime.h>

#define NB 2
#define C 32
#define H 128
#define W 256
#define D 48
#define HW (H * W)

// ---------------------------------------------------------------------------
// zkern v9: z[n][d][h][w] = sum_c x[n][c][h][w]*y[n][c][h][w-d]  (0 if w<d)
// Grid NB*H (=256 blocks) x 384 threads (6 waves, 1 block/CU, 1.5 waves/SIMD
// — same residency as v6 but y staged ONCE per (n,h) instead of twice).
// Thread = (w-quad q 0..63, dgroup dg 0..5); dg owns d0=8*dg..d0+7.
// ys[c][col] <-> y idx col-48 (cols 0..47 = zero pad). Window start
// S0 = 4q+40-d0 is 16B-aligned -> 3 ds_read_b128 per c serve 4w x 8d FMAs.
// Burst x-loads 16-deep (one latency exposure per 16 channels).
// Same c-summation order as v6 -> bit-identical z.
// ---------------------------------------------------------------------------
__global__ __launch_bounds__(384) void zkern(const float* __restrict__ x,
                                             const float* __restrict__ y,
                                             float* __restrict__ z) {
    const int s    = blockIdx.x;
    const int xcd  = s & 7;
    const int slot = s >> 3;        // 0..31
    const int hi   = slot & 15;
    const int n    = slot >> 4;
    const int h    = xcd * 16 + hi;

    const int tid  = threadIdx.x;
    const int q    = tid & 63;      // w-quad: w = 4q+o
    const int dg   = tid >> 6;      // 0..5
    const int d0   = dg * 8;

    __shared__ __align__(16) float ys[C][304];  // col <-> y idx col-48

    const float* xrow = x + ((size_t)(n * C) * H + h) * (size_t)W;
    const float* yrow = y + ((size_t)(n * C) * H + h) * (size_t)W;

    // stage: 32 rows x 76 float4 (first 12 f4 = zero pad)
#pragma unroll
    for (int it = 0; it < 7; ++it) {
        const int idx = it * 384 + tid;
        if (idx < 32 * 76) {
            const int r  = idx / 76;
            const int c4 = idx % 76;
            float4 v = {0.f, 0.f, 0.f, 0.f};
            if (c4 >= 12) v = *(const float4*)(yrow + (size_t)r * HW + 4 * c4 - 48);
            *(float4*)&ys[r][4 * c4] = v;
        }
    }
    __syncthreads();

    float acc[8][4] = {};
    const int S0 = 4 * q + 40 - d0;   // 0..292, 16B-aligned, S0+11 <= 303
    const float* xcol = xrow + 4 * q;

#pragma unroll
    for (int cb = 0; cb < 2; ++cb) {
        float4 xr[16];
#pragma unroll
        for (int t = 0; t < 16; ++t)
            xr[t] = *(const float4*)(xcol + (size_t)(cb * 16 + t) * HW);

#pragma unroll
        for (int t = 0; t < 16; ++t) {
            const int c = cb * 16 + t;
            const float4 w0 = *(const float4*)&ys[c][S0];
            const float4 w1 = *(const float4*)&ys[c][S0 + 4];
            const float4 w2 = *(const float4*)&ys[c][S0 + 8];
            const float win[12] = {w0.x, w0.y, w0.z, w0.w,
                                   w1.x, w1.y, w1.z, w1.w,
                                   w2.x, w2.y, w2.z, w2.w};
            const float xs[4] = {xr[t].x, xr[t].y, xr[t].z, xr[t].w};
            // acc[k][o] += x[4q+o] * y[4q+o-(d0+k)] ; col = 4q+o-(d0+k)+48 = S0+8+o-k
#pragma unroll
            for (int k = 0; k < 8; ++k)
#pragma unroll
                for (int o = 0; o < 4; ++o)
                    acc[k][o] += xs[o] * win[8 + o - k];
        }
    }

    float* zp = z + (((size_t)n * D + d0) * H + h) * (size_t)W + 4 * q;
#pragma unroll
    for (int k = 0; k < 8; ++k) {
        float4 v;
        v.x = acc[k][0]; v.y = acc[k][1]; v.z = acc[k][2]; v.w = acc[k][3];
        *(float4*)(zp + (size_t)k * HW) = v;
    }
}

// ---------------------------------------------------------------------------
// fkern v7 (byte-identical to round 9's 26.9us version, grid 768):
// parity-pair blocks; block = (xcd band, d-chunk, parity, pair, n);
// thread = (q, r, g2) -> 4 d x 4 w; 6 staged z-rows serve both output rows
// (l = i + r); taps duplicated only x2. LDS 50.7 KB, all ops b128.
// ---------------------------------------------------------------------------
#define DCH 8
#define NCH (D / DCH)   // 6
#define FGRID 768       // 8 xcd * NCH * 16 (p, pl, n)

__global__ __launch_bounds__(256) void fkern(const float* __restrict__ z,
                                             const float* __restrict__ Ff,
                                             const float* __restrict__ B,
                                             float* __restrict__ out) {
    __shared__ __align__(16) float zs[DCH][6][264];   // col 0 <-> w=-4

    const int s    = blockIdx.x;
    const int xcd  = s & 7;          // h-band = rows [16*xcd, 16*xcd+15]
    const int slot = s >> 3;         // 0..95
    const int ch   = slot % NCH;     // d-chunk
    const int t2   = slot / NCH;     // 0..15
    const int p    = t2 & 1;         // parity
    const int pl   = (t2 >> 1) & 3;  // pair index within band
    const int n    = t2 >> 3;        // batch
    const int h0   = xcd * 16 + 4 * pl + p;   // rows h0, h0+2
    const int d0   = ch * DCH;

    const int tid  = threadIdx.x;
    const int q    = tid & 63;        // w-quad: w = 4q+o
    const int r    = (tid >> 6) & 1;  // output row = h0 + 2r
    const int g2   = tid >> 7;        // d-half: d = d0 + 4*g2 + k
    const int hrow = h0 + 2 * r;

    // stage 48 rows (8 dd x 6 l) x 66 float4 ; l <-> hh = h0-4+2l
#pragma unroll
    for (int it = 0; it < 13; ++it) {
        const int idx = it * 256 + tid;
        if (idx < 48 * 66) {
            const int r2 = idx / 66;
            const int c4 = idx % 66;
            const int dd = r2 / 6;
            const int l  = r2 % 6;
            const int hh = h0 - 4 + 2 * l;
            float4 v = {0.f, 0.f, 0.f, 0.f};
            if (c4 >= 1 && c4 <= 64 && hh >= 0 && hh < H)
                v = *(const float4*)(z + (((size_t)n * D + d0 + dd) * H + hh) * (size_t)W
                                       + 4 * c4 - 4);
            *(float4*)&zs[dd][l][4 * c4] = v;
        }
    }

    const float4 bias = *(const float4*)(B + ((size_t)n * H + hrow) * (size_t)W + 4 * q);
    float acc[4][4];
#pragma unroll
    for (int k = 0; k < 4; ++k) {
        acc[k][0] = bias.x; acc[k][1] = bias.y;
        acc[k][2] = bias.z; acc[k][3] = bias.w;
    }

    __syncthreads();

#pragma unroll
    for (int i = 0; i < 5; ++i) {
        const int l = i + r;          // staged row serving tap-row i of row r
        float4 f[5];
#pragma unroll
        for (int jj = 0; jj < 5; ++jj)
            f[jj] = *(const float4*)(Ff + (((size_t)n * 25 + i * 5 + jj) * H + hrow) * (size_t)W
                                        + 4 * q);
        const float fs[5][4] = {
            {f[0].x, f[0].y, f[0].z, f[0].w},
            {f[1].x, f[1].y, f[1].z, f[1].w},
            {f[2].x, f[2].y, f[2].z, f[2].w},
            {f[3].x, f[3].y, f[3].z, f[3].w},
            {f[4].x, f[4].y, f[4].z, f[4].w}};

#pragma unroll
        for (int k = 0; k < 4; ++k) {
            const int dd = 4 * g2 + k;
            const float4 w0 = *(const float4*)&zs[dd][l][4 * q];
            const float4 w1 = *(const float4*)&zs[dd][l][4 * q + 4];
            const float4 w2 = *(const float4*)&zs[dd][l][4 * q + 8];
            const float win[12] = {w0.x, w0.y, w0.z, w0.w,
                                   w1.x, w1.y, w1.z, w1.w,
                                   w2.x, w2.y, w2.z, w2.w};
            // out[hrow][w=4q+o] += f[i*5+jj] * z[d][h0-4+2l][w+2jj-4] ; col 4q+o+2jj
#pragma unroll
            for (int jj = 0; jj < 5; ++jj)
#pragma unroll
                for (int o = 0; o < 4; ++o)
                    acc[k][o] += fs[jj][o] * win[o + 2 * jj];
        }
    }

#pragma unroll
    for (int k = 0; k < 4; ++k) {
        float* op = out + (((size_t)n * D + d0 + 4 * g2 + k) * H + hrow) * (size_t)W + 4 * q;
        float4 v;
        v.x = acc[k][0]; v.y = acc[k][1]; v.z = acc[k][2]; v.w = acc[k][3];
        *(float4*)op = v;
    }
}

// ---------------------------------------------------------------------------
// Fallback (workspace too small): fully fused naive version. Correctness only.
// ---------------------------------------------------------------------------
__global__ __launch_bounds__(256) void fused_naive(const float* __restrict__ x,
                                                   const float* __restrict__ y,
                                                   const float* __restrict__ Ff,
                                                   const float* __restrict__ B,
                                                   float* __restrict__ out) {
    const size_t idx = (size_t)blockIdx.x * 256 + threadIdx.x;
    if (idx >= (size_t)NB * D * H * W) return;
    const int w = (int)(idx % W);
    const int h = (int)((idx / W) % H);
    const int d = (int)((idx / ((size_t)W * H)) % D);
    const int n = (int)(idx / ((size_t)W * H * D));

    float acc = B[((size_t)n * H + h) * W + w];
#pragma unroll
    for (int i = 0; i < 5; ++i) {
        const int hh = h + 2 * i - 4;
        if (hh < 0 || hh >= H) continue;
#pragma unroll
        for (int j = 0; j < 5; ++j) {
            const int ww = w + 2 * j - 4;
            if (ww < 0 || ww >= W) continue;
            const int ws_ = ww - d;
            float zv = 0.f;
            if (ws_ >= 0) {
                const float* xp = x + (((size_t)n * C) * H + hh) * (size_t)W + ww;
                const float* yp = y + (((size_t)n * C) * H + hh) * (size_t)W + ws_;
                for (int c = 0; c < C; ++c)
                    zv += xp[(size_t)c * HW] * yp[(size_t)c * HW];
            }
            acc += Ff[(((size_t)n * 25 + i * 5 + j) * H + h) * (size_t)W + w] * zv;
        }
    }
    out[idx] = acc;
}

extern "C" void kernel_launch(void* const* d_in, const int* in_sizes, int n_in,
                              void* d_out, int out_size, void* d_ws, size_t ws_size,
                              hipStream_t stream) {
    const float* x = (const float*)d_in[0];
    const float* y = (const float*)d_in[1];
    const float* F = (const float*)d_in[2];
    const float* B = (const float*)d_in[3];
    float* out = (float*)d_out;

    const size_t zbytes = (size_t)NB * D * H * W * sizeof(float);

    if (ws_size >= zbytes) {
        float* z = (float*)d_ws;
        zkern<<<NB * H, 384, 0, stream>>>(x, y, z);
        fkern<<<FGRID, 256, 0, stream>>>(z, F, B, out);
    } else {
        const size_t total = (size_t)NB * D * H * W;
        fused_naive<<<(int)((total + 255) / 256), 256, 0, stream>>>(x, y, F, B, out);
    }
}

// Round 14
// 26.213 us; speedup vs baseline: 3.4832x; 1.0080x over previous
//
#include <hip/hip_runtime.h>

#define NB 2
#define C 32
#define H 128
#define W 256
#define D 48
#define HW (H * W)

// ---------------------------------------------------------------------------
// zkern v9 (byte-identical to round 13's 26.4us version):
// z[n][d][h][w] = sum_c x[n][c][h][w]*y[n][c][h][w-d]  (0 if w<d)
// Grid NB*H (=256) x 384 threads; y staged once per (n,h); 3 b128/c -> 32 FMA;
// burst x-loads 16-deep; XCD h-band swizzle.
// ---------------------------------------------------------------------------
__global__ __launch_bounds__(384) void zkern(const float* __restrict__ x,
                                             const float* __restrict__ y,
                                             float* __restrict__ z) {
    const int s    = blockIdx.x;
    const int xcd  = s & 7;
    const int slot = s >> 3;        // 0..31
    const int hi   = slot & 15;
    const int n    = slot >> 4;
    const int h    = xcd * 16 + hi;

    const int tid  = threadIdx.x;
    const int q    = tid & 63;      // w-quad: w = 4q+o
    const int dg   = tid >> 6;      // 0..5
    const int d0   = dg * 8;

    __shared__ __align__(16) float ys[C][304];  // col <-> y idx col-48

    const float* xrow = x + ((size_t)(n * C) * H + h) * (size_t)W;
    const float* yrow = y + ((size_t)(n * C) * H + h) * (size_t)W;

    // stage: 32 rows x 76 float4 (first 12 f4 = zero pad)
#pragma unroll
    for (int it = 0; it < 7; ++it) {
        const int idx = it * 384 + tid;
        if (idx < 32 * 76) {
            const int r  = idx / 76;
            const int c4 = idx % 76;
            float4 v = {0.f, 0.f, 0.f, 0.f};
            if (c4 >= 12) v = *(const float4*)(yrow + (size_t)r * HW + 4 * c4 - 48);
            *(float4*)&ys[r][4 * c4] = v;
        }
    }
    __syncthreads();

    float acc[8][4] = {};
    const int S0 = 4 * q + 40 - d0;   // 0..292, 16B-aligned
    const float* xcol = xrow + 4 * q;

#pragma unroll
    for (int cb = 0; cb < 2; ++cb) {
        float4 xr[16];
#pragma unroll
        for (int t = 0; t < 16; ++t)
            xr[t] = *(const float4*)(xcol + (size_t)(cb * 16 + t) * HW);

#pragma unroll
        for (int t = 0; t < 16; ++t) {
            const int c = cb * 16 + t;
            const float4 w0 = *(const float4*)&ys[c][S0];
            const float4 w1 = *(const float4*)&ys[c][S0 + 4];
            const float4 w2 = *(const float4*)&ys[c][S0 + 8];
            const float win[12] = {w0.x, w0.y, w0.z, w0.w,
                                   w1.x, w1.y, w1.z, w1.w,
                                   w2.x, w2.y, w2.z, w2.w};
            const float xs[4] = {xr[t].x, xr[t].y, xr[t].z, xr[t].w};
#pragma unroll
            for (int k = 0; k < 8; ++k)
#pragma unroll
                for (int o = 0; o < 4; ++o)
                    acc[k][o] += xs[o] * win[8 + o - k];
        }
    }

    float* zp = z + (((size_t)n * D + d0) * H + h) * (size_t)W + 4 * q;
#pragma unroll
    for (int k = 0; k < 8; ++k) {
        float4 v;
        v.x = acc[k][0]; v.y = acc[k][1]; v.z = acc[k][2]; v.w = acc[k][3];
        *(float4*)(zp + (size_t)k * HW) = v;
    }
}

// ---------------------------------------------------------------------------
// fkern v8: 4-row same-parity groups, taps loaded exactly once per thread.
// Block = (xcd band, 6-d chunk ch 0..7, parity p, group pl, n) -> 512 blocks.
// Rows {h0, h0+2, h0+4, h0+6}, h0 = 16*xcd + 8*pl + p. Thread = (q 0..63,
// r 0..3) owns 6 d x 4 w of output row h0+2r. Staged rows l = r+i (0..7),
// hh = h0-4+2l, serve all 4 output rows -> z re-read 3x -> 2x; taps x1.
// LDS zs[6][8][264] = 49.5 KB; all LDS ops lane-contiguous b128.
// ---------------------------------------------------------------------------
#define DCH 6
#define NCH (D / DCH)   // 8
#define FGRID 512       // 8 xcd * 8 ch * 2 p * 2 pl * 2 n

__global__ __launch_bounds__(256) void fkern(const float* __restrict__ z,
                                             const float* __restrict__ Ff,
                                             const float* __restrict__ B,
                                             float* __restrict__ out) {
    __shared__ __align__(16) float zs[DCH][8][264];   // col 0 <-> w=-4

    const int s    = blockIdx.x;
    const int xcd  = s & 7;          // h-band = rows [16*xcd, 16*xcd+15]
    const int slot = s >> 3;         // 0..63
    const int ch   = slot & 7;       // d-chunk of 6
    const int t2   = slot >> 3;      // 0..7
    const int p    = t2 & 1;         // parity
    const int pl   = (t2 >> 1) & 1;  // group within band
    const int n    = t2 >> 2;        // batch
    const int h0   = xcd * 16 + 8 * pl + p;   // rows h0, h0+2, h0+4, h0+6
    const int d0   = ch * DCH;

    const int tid  = threadIdx.x;
    const int q    = tid & 63;       // w-quad: w = 4q+o
    const int r    = tid >> 6;       // 0..3 ; output row = h0 + 2r
    const int hrow = h0 + 2 * r;

    // stage 48 rows (6 dd x 8 l) x 66 float4 ; l <-> hh = h0-4+2l
#pragma unroll
    for (int it = 0; it < 13; ++it) {
        const int idx = it * 256 + tid;
        if (idx < 48 * 66) {
            const int r2 = idx / 66;
            const int c4 = idx % 66;
            const int dd = r2 >> 3;       // 0..5
            const int l  = r2 & 7;        // 0..7
            const int hh = h0 - 4 + 2 * l;
            float4 v = {0.f, 0.f, 0.f, 0.f};
            if (c4 >= 1 && c4 <= 64 && hh >= 0 && hh < H)
                v = *(const float4*)(z + (((size_t)n * D + d0 + dd) * H + hh) * (size_t)W
                                       + 4 * c4 - 4);
            *(float4*)&zs[dd][l][4 * c4] = v;
        }
    }

    const float4 bias = *(const float4*)(B + ((size_t)n * H + hrow) * (size_t)W + 4 * q);
    float acc[DCH][4];
#pragma unroll
    for (int k = 0; k < DCH; ++k) {
        acc[k][0] = bias.x; acc[k][1] = bias.y;
        acc[k][2] = bias.z; acc[k][3] = bias.w;
    }

    __syncthreads();

#pragma unroll
    for (int i = 0; i < 5; ++i) {
        const int l = i + r;          // staged row serving tap-row i of row r
        float4 f[5];
#pragma unroll
        for (int jj = 0; jj < 5; ++jj)
            f[jj] = *(const float4*)(Ff + (((size_t)n * 25 + i * 5 + jj) * H + hrow) * (size_t)W
                                        + 4 * q);
        const float fs[5][4] = {
            {f[0].x, f[0].y, f[0].z, f[0].w},
            {f[1].x, f[1].y, f[1].z, f[1].w},
            {f[2].x, f[2].y, f[2].z, f[2].w},
            {f[3].x, f[3].y, f[3].z, f[3].w},
            {f[4].x, f[4].y, f[4].z, f[4].w}};

#pragma unroll
        for (int k = 0; k < DCH; ++k) {
            const float4 w0 = *(const float4*)&zs[k][l][4 * q];
            const float4 w1 = *(const float4*)&zs[k][l][4 * q + 4];
            const float4 w2 = *(const float4*)&zs[k][l][4 * q + 8];
            const float win[12] = {w0.x, w0.y, w0.z, w0.w,
                                   w1.x, w1.y, w1.z, w1.w,
                                   w2.x, w2.y, w2.z, w2.w};
            // out[hrow][w=4q+o] += f[i*5+jj] * z[d0+k][h0-4+2l][w+2jj-4] ; col 4q+o+2jj
#pragma unroll
            for (int jj = 0; jj < 5; ++jj)
#pragma unroll
                for (int o = 0; o < 4; ++o)
                    acc[k][o] += fs[jj][o] * win[o + 2 * jj];
        }
    }

#pragma unroll
    for (int k = 0; k < DCH; ++k) {
        float* op = out + (((size_t)n * D + d0 + k) * H + hrow) * (size_t)W + 4 * q;
        float4 v;
        v.x = acc[k][0]; v.y = acc[k][1]; v.z = acc[k][2]; v.w = acc[k][3];
        *(float4*)op = v;
    }
}

// ---------------------------------------------------------------------------
// Fallback (workspace too small): fully fused naive version. Correctness only.
// ---------------------------------------------------------------------------
__global__ __launch_bounds__(256) void fused_naive(const float* __restrict__ x,
                                                   const float* __restrict__ y,
                                                   const float* __restrict__ Ff,
                                                   const float* __restrict__ B,
                                                   float* __restrict__ out) {
    const size_t idx = (size_t)blockIdx.x * 256 + threadIdx.x;
    if (idx >= (size_t)NB * D * H * W) return;
    const int w = (int)(idx % W);
    const int h = (int)((idx / W) % H);
    const int d = (int)((idx / ((size_t)W * H)) % D);
    const int n = (int)(idx / ((size_t)W * H * D));

    float acc = B[((size_t)n * H + h) * W + w];
#pragma unroll
    for (int i = 0; i < 5; ++i) {
        const int hh = h + 2 * i - 4;
        if (hh < 0 || hh >= H) continue;
#pragma unroll
        for (int j = 0; j < 5; ++j) {
            const int ww = w + 2 * j - 4;
            if (ww < 0 || ww >= W) continue;
            const int ws_ = ww - d;
            float zv = 0.f;
            if (ws_ >= 0) {
                const float* xp = x + (((size_t)n * C) * H + hh) * (size_t)W + ww;
                const float* yp = y + (((size_t)n * C) * H + hh) * (size_t)W + ws_;
                for (int c = 0; c < C; ++c)
                    zv += xp[(size_t)c * HW] * yp[(size_t)c * HW];
            }
            acc += Ff[(((size_t)n * 25 + i * 5 + j) * H + h) * (size_t)W + w] * zv;
        }
    }
    out[idx] = acc;
}

extern "C" void kernel_launch(void* const* d_in, const int* in_sizes, int n_in,
                              void* d_out, int out_size, void* d_ws, size_t ws_size,
                              hipStream_t stream) {
    const float* x = (const float*)d_in[0];
    const float* y = (const float*)d_in[1];
    const float* F = (const float*)d_in[2];
    const float* B = (const float*)d_in[3];
    float* out = (float*)d_out;

    const size_t zbytes = (size_t)NB * D * H * W * sizeof(float);

    if (ws_size >= zbytes) {
        float* z = (float*)d_ws;
        zkern<<<NB * H, 384, 0, stream>>>(x, y, z);
        fkern<<<FGRID, 256, 0, stream>>>(z, F, B, out);
    } else {
        const size_t total = (size_t)NB * D * H * W;
        fused_naive<<<(int)((total + 255) / 256), 256, 0, stream>>>(x, y, F, B, out);
    }
}